// Round 5
// baseline (191.934 us; speedup 1.0000x reference)
//
#include <hip/hip_runtime.h>
#include <stdint.h>

#define DEV __device__ __forceinline__

typedef float f32x4 __attribute__((ext_vector_type(4)));
typedef __bf16 bf16x8 __attribute__((ext_vector_type(8)));
typedef short short8 __attribute__((ext_vector_type(8)));
typedef short short4v __attribute__((ext_vector_type(4)));

DEV unsigned short f2bf(float f) {
    union { float f; unsigned u; } c; c.f = f;
    unsigned u = c.u;
    u += 0x7fffu + ((u >> 16) & 1u);   // round-to-nearest-even
    return (unsigned short)(u >> 16);
}
DEV void async_ld16(const void* g, void* l) {
    __builtin_amdgcn_global_load_lds(
        (const __attribute__((address_space(1))) unsigned int*)g,
        (__attribute__((address_space(3))) unsigned int*)l, 16, 0, 0);
}
DEV f32x4 mfma16(bf16x8 a, bf16x8 b, f32x4 c) {
    return __builtin_amdgcn_mfma_f32_16x16x32_bf16(a, b, c, 0, 0, 0);
}

// ---------------- k_prep: x->bf16 + W de-interleaved transpose --------------
// blocks [0,4096): x cvt; [4096,4864): W -> Wt[3][1024][1024]
__global__ __launch_bounds__(256) void k_prep(const float* __restrict__ x,
                                              const float* __restrict__ W,
                                              unsigned short* __restrict__ xb,
                                              unsigned short* __restrict__ Wt) {
    __shared__ float T[64][65];
    const int blk = blockIdx.x, t = threadIdx.x;
    if (blk < 4096) {
        int i = blk * 256 + t;
        const float4* xp = (const float4*)x;
        float4 a = xp[i * 2], b = xp[i * 2 + 1];
        short8 o;
        o[0] = (short)f2bf(a.x); o[1] = (short)f2bf(a.y);
        o[2] = (short)f2bf(a.z); o[3] = (short)f2bf(a.w);
        o[4] = (short)f2bf(b.x); o[5] = (short)f2bf(b.y);
        o[6] = (short)f2bf(b.z); o[7] = (short)f2bf(b.w);
        *(short8*)(xb + i * 8) = o;
    } else {
        int bx = blk - 4096;
        int k0 = (bx / 48) * 64, n0 = (bx % 48) * 64;
        int rr = t >> 4, c4 = (t & 15) * 4;
        for (int i = 0; i < 4; i++) {
            int row = rr + i * 16;
            float4 v = *(const float4*)(W + (unsigned)(k0 + row) * 3072u + n0 + c4);
            T[row][c4] = v.x; T[row][c4 + 1] = v.y; T[row][c4 + 2] = v.z; T[row][c4 + 3] = v.w;
        }
        __syncthreads();
        for (int i = 0; i < 4; i++) {
            int ncol = rr + i * 16;
            int n = n0 + ncol;
            int which = n % 3;
            int oc = (n / 192) * 64 + (n % 192) / 3;
            short4v o;
            o[0] = (short)f2bf(T[c4 + 0][ncol]);
            o[1] = (short)f2bf(T[c4 + 1][ncol]);
            o[2] = (short)f2bf(T[c4 + 2][ncol]);
            o[3] = (short)f2bf(T[c4 + 3][ncol]);
            *(short4v*)(Wt + (unsigned)which * 1048576u + (unsigned)oc * 1024u + k0 + c4) = o;
        }
    }
}

// ---------------- k_qkv: combined QKV projection, 256x256 tile --------------
// BM=BN=256, BK=64. 512 thr = 8 waves (2M x 4N), per-wave 128x64 (acc[8][4]).
// LDS: [2][256][64] dbuf for A(X tokens) and B(W cols) = 128KB, round-3's
// PROVEN chunk-XOR involution (stage source chunk = scs ^ (row&7); frag read
// chunk = c0 ^ (row&7)) -> measured 0 bank conflicts; global_load_lds dest
// stays lane-linear. Pipeline: STAGE(kt+1) -> vmcnt(8) (retires exactly tile
// kt; never drains in main loop) -> barrier -> compute K=64 -> barrier.
// Race-free: buf^1's last reader finished before iter kt-1's trailing
// barrier; overwrite issued after it. Grid 384 = 32 Mtiles x 12 Ntiles
// (plane = ntile>>2), XCD-bijective swizzle (384%8==0). Plane 0 (Q) swaps
// MFMA operands so acc reg-dim = outcols (packed Qs stores); planes 1/2
// keep A=tokens (packed transposed K/V stores).
#define BARRIER() asm volatile("s_barrier" ::: "memory")
#define WAITV(n) do { asm volatile("s_waitcnt vmcnt(" #n ")" ::: "memory"); \
                      __builtin_amdgcn_sched_barrier(0); } while (0)

__global__ __launch_bounds__(512, 2) void k_qkv(const unsigned short* __restrict__ xb,
                                                const unsigned short* __restrict__ Wt,
                                                const float* __restrict__ bias,
                                                unsigned short* __restrict__ Qs,
                                                unsigned short* __restrict__ K,
                                                unsigned short* __restrict__ V) {
    __shared__ __align__(16) unsigned short As[2][256 * 64];   // 64KB X tokens
    __shared__ __align__(16) unsigned short Bs[2][256 * 64];   // 64KB W cols

    // XCD-contiguous bijective remap (384 % 8 == 0, chunk 48)
    const int o = blockIdx.x;
    const int w = (o & 7) * 48 + (o >> 3);
    const int mtile = w & 31, ntile = w >> 5;   // 32 x 12
    const int m0 = mtile * 256;                 // token base
    const int plane = ntile >> 2;               // 0=Q 1=K 2=V
    const int pc0 = (ntile & 3) * 256;          // col base within plane
    const unsigned short* Xp = xb + (unsigned)m0 * 1024u;
    const unsigned short* Wp = Wt + (unsigned)plane * 1048576u + (unsigned)pc0 * 1024u;

    const int t = threadIdx.x;
    const int wave = t >> 6, lane = t & 63;
    const int lan15 = lane & 15, quad = lane >> 4;
    const int slr = t >> 3;                   // staging row-in-64 (0..63)
    const int scs = t & 7;                    // staging 16B chunk (0..7)

    // operand roles: plane 0 swapped (A-operand = W cols), else A = tokens
    const bool swp = (plane == 0);
    const int aRow0 = (wave & 1) * 128;       // A-operand-side 128-row group
    const int bRow0 = (wave >> 1) * 64;       // B-operand-side 64-row group

    f32x4 acc[8][4] = {};

    // stage one full K-tile (A 32KB + B 32KB); 8 loads/thread.
    // dest lane-linear per wave (rows i*64+wave*8..+8); source chunk-XOR'd.
#define STAGE(kt, bf) do {                                                    \
        const unsigned ko_ = (unsigned)((kt) * 64);                           \
        _Pragma("unroll")                                                     \
        for (int i_ = 0; i_ < 4; i_++) {                                      \
            int r_ = i_ * 64 + slr;                                           \
            int c_ = scs ^ (r_ & 7);                                          \
            async_ld16(Xp + (unsigned)r_ * 1024u + ko_ + c_ * 8,              \
                       (void*)(As[bf] + (i_ * 64 + wave * 8) * 64));          \
            async_ld16(Wp + (unsigned)r_ * 1024u + ko_ + c_ * 8,              \
                       (void*)(Bs[bf] + (i_ * 64 + wave * 8) * 64));          \
        }                                                                     \
    } while (0)

    STAGE(0, 0);

    for (int kt = 0; kt < 16; kt++) {
        const int buf = kt & 1;
        if (kt < 15) { STAGE(kt + 1, buf ^ 1); WAITV(8); }
        else         { WAITV(0); }
        BARRIER();

        const unsigned short* Aop = swp ? Bs[buf] : As[buf];
        const unsigned short* Bop = swp ? As[buf] : Bs[buf];
#pragma unroll
        for (int ks = 0; ks < 2; ks++) {
            const int c0 = ks * 4 + quad;
            bf16x8 af[8], bfr[4];
#pragma unroll
            for (int tn = 0; tn < 4; tn++) {
                int row = bRow0 + tn * 16 + lan15;
                bfr[tn] = *(const bf16x8*)(Bop + row * 64 + (c0 ^ (row & 7)) * 8);
            }
#pragma unroll
            for (int tm = 0; tm < 8; tm++) {
                int row = aRow0 + tm * 16 + lan15;
                af[tm] = *(const bf16x8*)(Aop + row * 64 + (c0 ^ (row & 7)) * 8);
            }
            __builtin_amdgcn_s_setprio(1);
#pragma unroll
            for (int tm = 0; tm < 8; tm++)
#pragma unroll
                for (int tn = 0; tn < 4; tn++)
                    acc[tm][tn] = mfma16(af[tm], bfr[tn], acc[tm][tn]);
            __builtin_amdgcn_s_setprio(0);
        }
        BARRIER();
    }
#undef STAGE

    if (plane == 0) {
        // acc[tm][*]: tm/quad/reg = outcol (A-side 128 cols); tn/lan15 = token
        const int cg = (wave & 1) * 128;
        const int tg = (wave >> 1) * 64;
#pragma unroll
        for (int tm = 0; tm < 8; tm++) {
            int c4 = pc0 + cg + tm * 16 + quad * 4;   // 4-aligned, within one head
            int h = c4 >> 6, dd = c4 & 63;
            float b0 = bias[h * 192 + (dd + 0) * 3];
            float b1 = bias[h * 192 + (dd + 1) * 3];
            float b2 = bias[h * 192 + (dd + 2) * 3];
            float b3 = bias[h * 192 + (dd + 3) * 3];
#pragma unroll
            for (int tn = 0; tn < 4; tn++) {
                int token = m0 + tg + tn * 16 + lan15;
                unsigned bb = (unsigned)(token >> 11), tl = (unsigned)(token & 2047);
                uint2 p;
                p.x = (unsigned)f2bf((acc[tm][tn][0] + b0) * 32.0f) |
                      ((unsigned)f2bf((acc[tm][tn][1] + b1) * 32.0f) << 16);
                p.y = (unsigned)f2bf((acc[tm][tn][2] + b2) * 32.0f) |
                      ((unsigned)f2bf((acc[tm][tn][3] + b3) * 32.0f) << 16);
                *(uint2*)(Qs + bb * 2097152u + tl * 1024u + c4) = p;
            }
        }
    } else {
        // acc[tm][*]: tm/quad/reg = token (A-side 128 rows); tn/lan15 = KV col
        unsigned short* dst = (plane == 1) ? K : V;
        const int tg = (wave & 1) * 128;
        const int cg = (wave >> 1) * 64;
        const int batch = m0 >> 11;
#pragma unroll
        for (int tn = 0; tn < 4; tn++) {
            int cip = pc0 + cg + tn * 16 + lan15;     // col in plane
            int h = cip >> 6, d = cip & 63;
            float bv = bias[h * 192 + d * 3 + plane];
            unsigned kv_base = ((unsigned)(batch * 16 + h) * 64u + (unsigned)d) * 2048u;
#pragma unroll
            for (int tm = 0; tm < 8; tm++) {
                unsigned token0 = (unsigned)((m0 + tg + tm * 16 + quad * 4) & 2047);
                uint2 p;
                p.x = (unsigned)f2bf(acc[tm][tn][0] + bv) |
                      ((unsigned)f2bf(acc[tm][tn][1] + bv) << 16);
                p.y = (unsigned)f2bf(acc[tm][tn][2] + bv) |
                      ((unsigned)f2bf(acc[tm][tn][3] + bv) << 16);
                *(uint2*)(dst + kv_base + token0) = p;
            }
        }
    }
}

// ---------------- k_attn4: redundant M = K^T V (async-staged), out = Q.M ----
// grid 512: bh = blockIdx & 63 (XCD swizzle), sub = blockIdx >> 6.
__global__ __launch_bounds__(256) void k_attn4(const unsigned short* __restrict__ Kt,
                                               const unsigned short* __restrict__ Vt,
                                               const unsigned short* __restrict__ Qs,
                                               float* __restrict__ out) {
    __shared__ __align__(16) unsigned short Ks[64 * 128];   // 16KB [d][tok]
    __shared__ __align__(16) unsigned short Vs[64 * 128];   // 16KB [d][tok]
    __shared__ __align__(16) unsigned short Msb[64 * 64];   // 8KB [d2][d1]
    const int bh = blockIdx.x & 63, sub = blockIdx.x >> 6;
    const int b = bh >> 4, h = bh & 15;
    const int wave = threadIdx.x >> 6, lane = threadIdx.x & 63;
    const int lan15 = lane & 15, quad = lane >> 4;
    const unsigned base = (unsigned)bh * 131072u;
    const int mt0 = (wave & 1) * 2, nt0 = (wave >> 1) * 2;   // wave's 2x2 tiles
    const int slr = wave * 16 + (lane >> 4), scs = lane & 15;

    f32x4 macc[2][2] = {};
    for (int j = 0; j < 16; j++) {
        __syncthreads();
        for (int i = 0; i < 4; i++) {
            int lr = slr + i * 4;
            int c = scs ^ (lr & 15);
            async_ld16(Kt + base + (unsigned)lr * 2048u + j * 128 + c * 8,
                       (void*)(Ks + (wave * 16 + i * 4) * 128));
            async_ld16(Vt + base + (unsigned)lr * 2048u + j * 128 + c * 8,
                       (void*)(Vs + (wave * 16 + i * 4) * 128));
        }
        __syncthreads();
        for (int ks2 = 0; ks2 < 4; ks2++) {
            int c0 = ks2 * 4 + quad;
            bf16x8 ak[2], bv[2];
            for (int i = 0; i < 2; i++) {
                int row = (mt0 + i) * 16 + lan15;
                ak[i] = *(const bf16x8*)(Ks + row * 128 + (c0 ^ (row & 15)) * 8);
            }
            for (int i = 0; i < 2; i++) {
                int row = (nt0 + i) * 16 + lan15;
                bv[i] = *(const bf16x8*)(Vs + row * 128 + (c0 ^ (row & 15)) * 8);
            }
            for (int i = 0; i < 2; i++)
                for (int j2 = 0; j2 < 2; j2++)
                    macc[i][j2] = mfma16(ak[i], bv[j2], macc[i][j2]);
        }
    }
    // write M tiles: lane holds d1 = (mt0+i)*16 + quad*4 + r, d2 = (nt0+j2)*16+lan15
    for (int i = 0; i < 2; i++)
        for (int j2 = 0; j2 < 2; j2++) {
            int d2 = (nt0 + j2) * 16 + lan15;
            int c4 = ((mt0 + i) * 4 + quad) ^ (d2 & 15);
            uint2 p;
            p.x = (unsigned)f2bf(macc[i][j2][0]) | ((unsigned)f2bf(macc[i][j2][1]) << 16);
            p.y = (unsigned)f2bf(macc[i][j2][2]) | ((unsigned)f2bf(macc[i][j2][3]) << 16);
            *(uint2*)(Msb + d2 * 64 + c4 * 4) = p;
        }
    __syncthreads();

    // ---- phase B: out rows [sub*256 + wave*64, +64) = Q . M ----
    const int t0 = sub * 256 + wave * 64;
    f32x4 oacc[4][4] = {};
#pragma unroll
    for (int ks = 0; ks < 2; ks++) {
        bf16x8 af[4], bfr[4];
        for (int mt = 0; mt < 4; mt++) {
            int tok = t0 + mt * 16 + lan15;
            af[mt] = *(const bf16x8*)(Qs + (unsigned)b * 2097152u + (unsigned)tok * 1024u +
                                      h * 64 + ks * 32 + quad * 8);
        }
        for (int nt = 0; nt < 4; nt++) {
            int d2 = nt * 16 + lan15;
            int cA = ks * 8 + quad * 2;
            uint2 u0 = *(const uint2*)(Msb + d2 * 64 + ((cA) ^ (d2 & 15)) * 4);
            uint2 u1 = *(const uint2*)(Msb + d2 * 64 + ((cA + 1) ^ (d2 & 15)) * 4);
            union { uint4 u; bf16x8 v; } cv;
            cv.u.x = u0.x; cv.u.y = u0.y; cv.u.z = u1.x; cv.u.w = u1.y;
            bfr[nt] = cv.v;
        }
        for (int mt = 0; mt < 4; mt++)
            for (int nt = 0; nt < 4; nt++)
                oacc[mt][nt] = mfma16(af[mt], bfr[nt], oacc[mt][nt]);
    }
    for (int mt = 0; mt < 4; mt++)
        for (int nt = 0; nt < 4; nt++)
            for (int r = 0; r < 4; r++)
                out[base + (unsigned)(t0 + mt * 16 + quad * 4 + r) * 64u + nt * 16 + lan15] =
                    oacc[mt][nt][r];
}

extern "C" void kernel_launch(void* const* d_in, const int* in_sizes, int n_in,
                              void* d_out, int out_size, void* d_ws, size_t ws_size,
                              hipStream_t stream) {
    const float* x = (const float*)d_in[0];
    const float* W = (const float*)d_in[1];
    const float* b = (const float*)d_in[2];
    float* out = (float*)d_out;

    unsigned short* xb = (unsigned short*)d_ws;  // 8,388,608  [8192][1024] bf16
    unsigned short* Wt = xb + 8388608;           // 3,145,728  [3][1024][1024] bf16
    unsigned short* Qs = Wt + 3145728;           // 8,388,608  [4][2048][1024] bf16 (*32,+bias)
    unsigned short* Kt = Qs + 8388608;           // 8,388,608  [bh][d][n] bf16 (+bias)
    unsigned short* Vt = Kt + 8388608;           // 8,388,608  [bh][d][n] bf16 (+bias)
    // total: 73,400,320 bytes (known-safe)

    k_prep<<<4864, 256, 0, stream>>>(x, W, xb, Wt);
    k_qkv<<<384, 512, 0, stream>>>(xb, Wt, b, Qs, Kt, Vt);
    k_attn4<<<512, 256, 0, stream>>>(Kt, Vt, Qs, out);
}

// Round 6
// 182.545 us; speedup vs baseline: 1.0514x; 1.0514x over previous
//
#include <hip/hip_runtime.h>
#include <stdint.h>

#define DEV __device__ __forceinline__

typedef float f32x4 __attribute__((ext_vector_type(4)));
typedef __bf16 bf16x8 __attribute__((ext_vector_type(8)));
typedef short short8 __attribute__((ext_vector_type(8)));
typedef short short4v __attribute__((ext_vector_type(4)));

DEV unsigned short f2bf(float f) {
    union { float f; unsigned u; } c; c.f = f;
    unsigned u = c.u;
    u += 0x7fffu + ((u >> 16) & 1u);   // round-to-nearest-even
    return (unsigned short)(u >> 16);
}
DEV void async_ld16(const void* g, void* l) {
    __builtin_amdgcn_global_load_lds(
        (const __attribute__((address_space(1))) unsigned int*)g,
        (__attribute__((address_space(3))) unsigned int*)l, 16, 0, 0);
}
DEV f32x4 mfma16(bf16x8 a, bf16x8 b, f32x4 c) {
    return __builtin_amdgcn_mfma_f32_16x16x32_bf16(a, b, c, 0, 0, 0);
}

// ---------------- k_prep: x->bf16 + W de-interleaved transpose --------------
// blocks [0,4096): x cvt; [4096,4864): W -> Wt[3][1024][1024]
__global__ __launch_bounds__(256) void k_prep(const float* __restrict__ x,
                                              const float* __restrict__ W,
                                              unsigned short* __restrict__ xb,
                                              unsigned short* __restrict__ Wt) {
    __shared__ float T[64][65];
    const int blk = blockIdx.x, t = threadIdx.x;
    if (blk < 4096) {
        int i = blk * 256 + t;
        const float4* xp = (const float4*)x;
        float4 a = xp[i * 2], b = xp[i * 2 + 1];
        short8 o;
        o[0] = (short)f2bf(a.x); o[1] = (short)f2bf(a.y);
        o[2] = (short)f2bf(a.z); o[3] = (short)f2bf(a.w);
        o[4] = (short)f2bf(b.x); o[5] = (short)f2bf(b.y);
        o[6] = (short)f2bf(b.z); o[7] = (short)f2bf(b.w);
        *(short8*)(xb + i * 8) = o;
    } else {
        int bx = blk - 4096;
        int k0 = (bx / 48) * 64, n0 = (bx % 48) * 64;
        int rr = t >> 4, c4 = (t & 15) * 4;
        for (int i = 0; i < 4; i++) {
            int row = rr + i * 16;
            float4 v = *(const float4*)(W + (unsigned)(k0 + row) * 3072u + n0 + c4);
            T[row][c4] = v.x; T[row][c4 + 1] = v.y; T[row][c4 + 2] = v.z; T[row][c4 + 3] = v.w;
        }
        __syncthreads();
        for (int i = 0; i < 4; i++) {
            int ncol = rr + i * 16;
            int n = n0 + ncol;
            int which = n % 3;
            int oc = (n / 192) * 64 + (n % 192) / 3;
            short4v o;
            o[0] = (short)f2bf(T[c4 + 0][ncol]);
            o[1] = (short)f2bf(T[c4 + 1][ncol]);
            o[2] = (short)f2bf(T[c4 + 2][ncol]);
            o[3] = (short)f2bf(T[c4 + 3][ncol]);
            *(short4v*)(Wt + (unsigned)which * 1048576u + (unsigned)oc * 1024u + k0 + c4) = o;
        }
    }
}

// ---------------- k_q: Qs[b][token][1024] = (x Wq + bq) * 32, packed --------
// Swapped operands (A=Wq rows -> m=outcol): lane's 4 accs = 4 consecutive
// outcols -> packed uint2 stores.  (R0-verified, 2 blocks/CU)
__global__ __launch_bounds__(256, 2) void k_q(const unsigned short* __restrict__ Wt,
                                              const unsigned short* __restrict__ xb,
                                              const float* __restrict__ bias,
                                              unsigned short* __restrict__ Qs) {
    __shared__ __align__(16) unsigned short As[128 * 64];
    __shared__ __align__(16) unsigned short Bs[128 * 64];
    const int m0 = blockIdx.x * 128;   // Q outcols
    const int n0 = blockIdx.y * 128;   // tokens
    const int wave = threadIdx.x >> 6, lane = threadIdx.x & 63;
    const int wm = (wave & 1) * 64, wn = (wave >> 1) * 64;
    const int lan15 = lane & 15, quad = lane >> 4;
    f32x4 acc[4][4] = {};
    const int slr = wave * 32 + (lane >> 3);
    const int scs = lane & 7;

    for (int kt = 0; kt < 16; kt++) {
        __syncthreads();
        for (int i = 0; i < 4; i++) {
            int lr = slr + i * 8;
            int c = scs ^ (lr & 7);
            async_ld16(Wt + (unsigned)(m0 + lr) * 1024u + kt * 64 + c * 8,
                       (void*)(As + (wave * 32 + i * 8) * 64));
            async_ld16(xb + (unsigned)(n0 + lr) * 1024u + kt * 64 + c * 8,
                       (void*)(Bs + (wave * 32 + i * 8) * 64));
        }
        __syncthreads();
        for (int ks = 0; ks < 2; ks++) {
            bf16x8 af[4], bfr[4];
            int c0 = ks * 4 + quad;
            for (int tm = 0; tm < 4; tm++) {
                int row = wm + tm * 16 + lan15;
                af[tm] = *(const bf16x8*)(As + row * 64 + (c0 ^ (row & 7)) * 8);
            }
            for (int tn = 0; tn < 4; tn++) {
                int row = wn + tn * 16 + lan15;
                bfr[tn] = *(const bf16x8*)(Bs + row * 64 + (c0 ^ (row & 7)) * 8);
            }
            for (int tm = 0; tm < 4; tm++)
                for (int tn = 0; tn < 4; tn++)
                    acc[tm][tn] = mfma16(af[tm], bfr[tn], acc[tm][tn]);
        }
    }

    for (int tm = 0; tm < 4; tm++) {
        int oc = m0 + wm + tm * 16 + quad * 4;      // aligned-4, within one head
        int h = oc >> 6, dd = oc & 63;
        float b0 = bias[h * 192 + (dd + 0) * 3];
        float b1 = bias[h * 192 + (dd + 1) * 3];
        float b2 = bias[h * 192 + (dd + 2) * 3];
        float b3 = bias[h * 192 + (dd + 3) * 3];
        for (int tn = 0; tn < 4; tn++) {
            int token = n0 + wn + tn * 16 + lan15;
            unsigned bb = (unsigned)(token >> 11), tl = (unsigned)(token & 2047);
            uint2 p;
            p.x = (unsigned)f2bf((acc[tm][tn][0] + b0) * 32.0f) |
                  ((unsigned)f2bf((acc[tm][tn][1] + b1) * 32.0f) << 16);
            p.y = (unsigned)f2bf((acc[tm][tn][2] + b2) * 32.0f) |
                  ((unsigned)f2bf((acc[tm][tn][3] + b3) * 32.0f) << 16);
            *(uint2*)(Qs + bb * 2097152u + tl * 1024u + oc) = p;
        }
    }
}

// ---------------- k_kv: K,V projections -> transposed [bh][d][n] ------------
// n0 in [0,2048): plane 1 (K) for n0<1024 else plane 2 (V). Uniform per block.
__global__ __launch_bounds__(256, 2) void k_kv(const unsigned short* __restrict__ xb,
                                               const unsigned short* __restrict__ Wt,
                                               const float* __restrict__ bias,
                                               unsigned short* __restrict__ K,
                                               unsigned short* __restrict__ V) {
    __shared__ __align__(16) unsigned short As[128 * 64];
    __shared__ __align__(16) unsigned short Bs[128 * 64];
    const int m0 = blockIdx.y * 128;           // tokens
    const int n0 = blockIdx.x * 128;           // KV cols
    const int plane = 1 + (n0 >> 10);          // 1=K, 2=V
    const int pc0 = n0 & 1023;
    const unsigned short* Wp = Wt + (unsigned)plane * 1048576u;
    const int wave = threadIdx.x >> 6, lane = threadIdx.x & 63;
    const int wm = (wave & 1) * 64, wn = (wave >> 1) * 64;
    const int lan15 = lane & 15, quad = lane >> 4;
    f32x4 acc[4][4] = {};
    const int slr = wave * 32 + (lane >> 3);
    const int scs = lane & 7;

    for (int kt = 0; kt < 16; kt++) {
        __syncthreads();
        for (int i = 0; i < 4; i++) {
            int lr = slr + i * 8;
            int c = scs ^ (lr & 7);
            async_ld16(xb + (unsigned)(m0 + lr) * 1024u + kt * 64 + c * 8,
                       (void*)(As + (wave * 32 + i * 8) * 64));
            async_ld16(Wp + (unsigned)(pc0 + lr) * 1024u + kt * 64 + c * 8,
                       (void*)(Bs + (wave * 32 + i * 8) * 64));
        }
        __syncthreads();
        for (int ks = 0; ks < 2; ks++) {
            bf16x8 af[4], bfr[4];
            int c0 = ks * 4 + quad;
            for (int tm = 0; tm < 4; tm++) {
                int row = wm + tm * 16 + lan15;
                af[tm] = *(const bf16x8*)(As + row * 64 + (c0 ^ (row & 7)) * 8);
            }
            for (int tn = 0; tn < 4; tn++) {
                int row = wn + tn * 16 + lan15;
                bfr[tn] = *(const bf16x8*)(Bs + row * 64 + (c0 ^ (row & 7)) * 8);
            }
            for (int tm = 0; tm < 4; tm++)
                for (int tn = 0; tn < 4; tn++)
                    acc[tm][tn] = mfma16(af[tm], bfr[tn], acc[tm][tn]);
        }
    }

    // epilogue: uniform class, packed 8B stores of 4 consecutive tokens
    const int batch = m0 >> 11;
    unsigned short* dst = (plane == 1) ? K : V;
    for (int tn = 0; tn < 4; tn++) {
        int cip = pc0 + wn + tn * 16 + lan15;       // col in plane
        int h = cip >> 6, d = cip & 63;
        float bv = bias[h * 192 + d * 3 + plane];
        unsigned kv_base = ((unsigned)(batch * 16 + h) * 64u + (unsigned)d) * 2048u;
        for (int tm = 0; tm < 4; tm++) {
            int rbase = m0 + wm + tm * 16 + quad * 4;
            unsigned token0 = (unsigned)(rbase & 2047);
            uint2 p;
            p.x = (unsigned)f2bf(acc[tm][tn][0] + bv) |
                  ((unsigned)f2bf(acc[tm][tn][1] + bv) << 16);
            p.y = (unsigned)f2bf(acc[tm][tn][2] + bv) |
                  ((unsigned)f2bf(acc[tm][tn][3] + bv) << 16);
            *(uint2*)(dst + kv_base + token0) = p;
        }
    }
}

// ---------------- k_m: partial M = K^T V over a 512-token chunk -------------
// grid 256: bh = blk & 63, chunk = blk >> 6. Phase-A structure of old k_attn4
// verbatim, j restricted to [chunk*4, chunk*4+4). Writes f32 partials
// Mp[bh][chunk][d2][d1] as float4 (d1 fastest). Removes the old 8x redundant
// M recompute + K/V staging.
__global__ __launch_bounds__(256) void k_m(const unsigned short* __restrict__ Kt,
                                           const unsigned short* __restrict__ Vt,
                                           float* __restrict__ Mp) {
    __shared__ __align__(16) unsigned short Ks[64 * 128];   // 16KB [d][tok]
    __shared__ __align__(16) unsigned short Vs[64 * 128];   // 16KB [d][tok]
    const int bh = blockIdx.x & 63, chunk = blockIdx.x >> 6;
    const int wave = threadIdx.x >> 6, lane = threadIdx.x & 63;
    const int lan15 = lane & 15, quad = lane >> 4;
    const unsigned base = (unsigned)bh * 131072u;
    const int mt0 = (wave & 1) * 2, nt0 = (wave >> 1) * 2;   // wave's 2x2 tiles
    const int slr = wave * 16 + (lane >> 4), scs = lane & 15;

    f32x4 macc[2][2] = {};
    for (int j = chunk * 4; j < chunk * 4 + 4; j++) {
        __syncthreads();
        for (int i = 0; i < 4; i++) {
            int lr = slr + i * 4;
            int c = scs ^ (lr & 15);
            async_ld16(Kt + base + (unsigned)lr * 2048u + j * 128 + c * 8,
                       (void*)(Ks + (wave * 16 + i * 4) * 128));
            async_ld16(Vt + base + (unsigned)lr * 2048u + j * 128 + c * 8,
                       (void*)(Vs + (wave * 16 + i * 4) * 128));
        }
        __syncthreads();
        for (int ks2 = 0; ks2 < 4; ks2++) {
            int c0 = ks2 * 4 + quad;
            bf16x8 ak[2], bv[2];
            for (int i = 0; i < 2; i++) {
                int row = (mt0 + i) * 16 + lan15;
                ak[i] = *(const bf16x8*)(Ks + row * 128 + (c0 ^ (row & 15)) * 8);
            }
            for (int i = 0; i < 2; i++) {
                int row = (nt0 + i) * 16 + lan15;
                bv[i] = *(const bf16x8*)(Vs + row * 128 + (c0 ^ (row & 15)) * 8);
            }
            for (int i = 0; i < 2; i++)
                for (int j2 = 0; j2 < 2; j2++)
                    macc[i][j2] = mfma16(ak[i], bv[j2], macc[i][j2]);
        }
    }
    // write partials: d1 = (mt0+i)*16 + quad*4 + r (reg), d2 = (nt0+j2)*16+lan15
    for (int i = 0; i < 2; i++)
        for (int j2 = 0; j2 < 2; j2++) {
            int d2 = (nt0 + j2) * 16 + lan15;
            int d1b = (mt0 + i) * 16 + quad * 4;
            *(f32x4*)(Mp + (((unsigned)(bh * 4 + chunk) * 64u + (unsigned)d2) * 64u + d1b)) =
                macc[i][j2];
        }
}

// ---------------- k_out: out = Q . M (M reduced from 4 partials) ------------
// grid 512: bh = blk & 63, sub = blk >> 6 (256 tokens each). Reduce Mp
// partials -> bf16 Msb[d2][d1] (4-chunk swizzle), then swapped-operand GEMM
// (A = M rows = d2) so acc regs = 4 consecutive d -> float4 stores.
__global__ __launch_bounds__(256) void k_out(const float* __restrict__ Mp,
                                             const unsigned short* __restrict__ Qs,
                                             float* __restrict__ out) {
    __shared__ __align__(16) unsigned short Msb[64 * 64];   // 8KB [d2][d1]
    const int bh = blockIdx.x & 63, sub = blockIdx.x >> 6;
    const int b = bh >> 4, h = bh & 15;
    const int wave = threadIdx.x >> 6, lane = threadIdx.x & 63;
    const int lan15 = lane & 15, quad = lane >> 4;
    const unsigned base = (unsigned)bh * 131072u;

    // reduce 4 partials: thread t -> d2 = t>>2, d1 block (t&3)*16
    {
        const int t = threadIdx.x;
        const int d2 = t >> 2, d1b = (t & 3) * 16;
        const float* mp0 = Mp + (((unsigned)(bh * 4) * 64u + (unsigned)d2) * 64u + d1b);
#pragma unroll
        for (int jj = 0; jj < 4; jj++) {
            float4 s = *(const float4*)(mp0 + jj * 4);
#pragma unroll
            for (int c = 1; c < 4; c++) {
                float4 v = *(const float4*)(mp0 + (unsigned)c * 4096u + jj * 4);
                s.x += v.x; s.y += v.y; s.z += v.z; s.w += v.w;
            }
            int c4 = (t & 3) * 4 + jj;
            uint2 p;
            p.x = (unsigned)f2bf(s.x) | ((unsigned)f2bf(s.y) << 16);
            p.y = (unsigned)f2bf(s.z) | ((unsigned)f2bf(s.w) << 16);
            *(uint2*)(Msb + d2 * 64 + (c4 ^ (d2 & 15)) * 4) = p;
        }
    }
    __syncthreads();

    // out rows [sub*256 + wave*64, +64) = Q . M  (A = M, m-index = d2)
    const int t0 = sub * 256 + wave * 64;
    f32x4 oacc[4][4] = {};
#pragma unroll
    for (int ks = 0; ks < 2; ks++) {
        bf16x8 mf[4], qf[4];
        for (int tm = 0; tm < 4; tm++) {
            int d2 = tm * 16 + lan15;
            int cA = ks * 8 + quad * 2;
            uint2 u0 = *(const uint2*)(Msb + d2 * 64 + ((cA) ^ (d2 & 15)) * 4);
            uint2 u1 = *(const uint2*)(Msb + d2 * 64 + ((cA + 1) ^ (d2 & 15)) * 4);
            union { uint4 u; bf16x8 v; } cv;
            cv.u.x = u0.x; cv.u.y = u0.y; cv.u.z = u1.x; cv.u.w = u1.y;
            mf[tm] = cv.v;
        }
        for (int tn = 0; tn < 4; tn++) {
            int tok = t0 + tn * 16 + lan15;
            qf[tn] = *(const bf16x8*)(Qs + (unsigned)b * 2097152u + (unsigned)tok * 1024u +
                                      h * 64 + ks * 32 + quad * 8);
        }
        for (int tm = 0; tm < 4; tm++)
            for (int tn = 0; tn < 4; tn++)
                oacc[tm][tn] = mfma16(mf[tm], qf[tn], oacc[tm][tn]);
    }
    // store: reg r = d2 = tm*16 + quad*4 + r; lan15 = token -> float4 per (tm,tn)
    for (int tm = 0; tm < 4; tm++)
        for (int tn = 0; tn < 4; tn++) {
            int tok = t0 + tn * 16 + lan15;
            int d2b = tm * 16 + quad * 4;
            *(f32x4*)(out + base + (unsigned)tok * 64u + d2b) = oacc[tm][tn];
        }
}

extern "C" void kernel_launch(void* const* d_in, const int* in_sizes, int n_in,
                              void* d_out, int out_size, void* d_ws, size_t ws_size,
                              hipStream_t stream) {
    const float* x = (const float*)d_in[0];
    const float* W = (const float*)d_in[1];
    const float* b = (const float*)d_in[2];
    float* out = (float*)d_out;

    unsigned short* xb = (unsigned short*)d_ws;  // 8,388,608  [8192][1024] bf16
    unsigned short* Wt = xb + 8388608;           // 3,145,728  [3][1024][1024] bf16
    unsigned short* Qs = Wt + 3145728;           // 8,388,608  [4][2048][1024] bf16 (*32,+bias)
    unsigned short* Kt = Qs + 8388608;           // 8,388,608  [bh][d][n] bf16 (+bias)
    unsigned short* Vt = Kt + 8388608;           // 8,388,608  [bh][d][n] bf16 (+bias)
    // total: 73,400,320 bytes (known-safe)
    // Mp (4 MB f32 partial M) aliases xb: xb is dead after k_q/k_kv complete,
    // and stream order serializes k_kv -> k_m.
    float* Mp = (float*)xb;

    k_prep<<<4864, 256, 0, stream>>>(x, W, xb, Wt);
    k_q<<<dim3(8, 64), 256, 0, stream>>>(Wt, xb, b, Qs);
    k_kv<<<dim3(16, 64), 256, 0, stream>>>(xb, Wt, b, Kt, Vt);
    k_m<<<256, 256, 0, stream>>>(Kt, Vt, Mp);
    k_out<<<512, 256, 0, stream>>>(Mp, Qs, out);
}